// Round 4
// baseline (185.143 us; speedup 1.0000x reference)
//
#include <hip/hip_runtime.h>
#include <stdint.h>

#define C   32
#define H   160
#define W   160
#define NB  32
#define HW  (H * W)          // 25600
#define CHW (C * HW)         // 819200
#define TH  8                // tile rows
#define TW  32               // tile cols
#define HALO_H (TH + 2)      // 10
#define HALO_W (TW + 2)      // 34
#define HALO_N (HALO_H * HALO_W)   // 340
#define TILES_H (H / TH)     // 20
#define TILES_W (W / TW)     // 5
#define TILES_PER_IMG (TILES_H * TILES_W)  // 100

// d_ws layout (uint32 units):
// [0,288)    w3bits  [oc*9 + kh*3 + kw], bit ic = (w3<0)
// [288,320)  w1bits  [oc], bit ic = (w1<0)
// [320,352)  scale3 (f32)   [352,384) shift3
// [384,416)  scale1 (f32)   [416,448) shift1

__global__ void pack_params(const float* __restrict__ w3,
                            const float* __restrict__ g3, const float* __restrict__ b3,
                            const float* __restrict__ m3, const float* __restrict__ v3,
                            const float* __restrict__ w1,
                            const float* __restrict__ g1, const float* __restrict__ b1,
                            const float* __restrict__ m1, const float* __restrict__ v1,
                            uint32_t* __restrict__ wsu) {
    int t = threadIdx.x;
    if (t < 288) {
        int oc = t / 9, tap = t % 9;
        uint32_t bits = 0;
#pragma unroll
        for (int ic = 0; ic < 32; ++ic)
            bits |= (w3[oc * 288 + ic * 9 + tap] < 0.0f) ? (1u << ic) : 0u;
        wsu[t] = bits;
    } else if (t < 320) {
        int oc = t - 288;
        uint32_t bits = 0;
#pragma unroll
        for (int ic = 0; ic < 32; ++ic)
            bits |= (w1[oc * 32 + ic] < 0.0f) ? (1u << ic) : 0u;
        wsu[288 + oc] = bits;
        float* f = (float*)wsu;
        float inv3 = g3[oc] * rsqrtf(v3[oc] + 1e-5f);
        f[320 + oc] = inv3;
        f[352 + oc] = b3[oc] - m3[oc] * inv3;
        float inv1 = g1[oc] * rsqrtf(v1[oc] + 1e-5f);
        f[384 + oc] = inv1;
        f[416 + oc] = b1[oc] - m1[oc] * inv1;
    }
}

// One block = 8x32 tile of one image, 1 px/thread, 256 threads (4 waves).
// Phase 1: pack sign bits of the 10x34 halo (row/col-clamped at image edges)
// into LDS. Phase 2: branch-free XNOR conv3x3 + BN + residual + 1x1 block.
// Image-border pixels get wrong values (clamped halo) and are overwritten by
// border_fix (stream-ordered after this kernel).
__global__ __launch_bounds__(256, 8) void fused_tile(const float* __restrict__ x,
                                                     const uint32_t* __restrict__ wsu,
                                                     float* __restrict__ out) {
    __shared__ uint32_t sbits[HALO_N];
    const float* wf = (const float*)wsu;
    int bid = blockIdx.x;
    int n   = bid / TILES_PER_IMG;
    int tt  = bid % TILES_PER_IMG;
    int tr  = tt / TILES_W;
    int tc  = tt % TILES_W;
    int h0  = tr * TH;
    int w0  = tc * TW;
    const float* xn = x + n * CHW;
    int t = threadIdx.x;

    // ---- phase 1: pack halo sign bits (340 positions, <=2 per thread) ----
    for (int p = t; p < HALO_N; p += 256) {
        int pr = p / HALO_W, pc = p % HALO_W;
        int hh = h0 - 1 + pr; hh = (hh < 0) ? 0 : (hh > H - 1 ? H - 1 : hh);
        int ww = w0 - 1 + pc; ww = (ww < 0) ? 0 : (ww > W - 1 ? W - 1 : ww);
        const float* xp = xn + hh * W + ww;
        uint32_t b = 0;
#pragma unroll
        for (int ch = 0; ch < 32; ++ch)
            b |= (xp[ch * HW] < 0.0f) ? (1u << ch) : 0u;
        sbits[p] = b;
    }
    __syncthreads();

    // ---- phase 2: conv + BN + residual + 1x1 block, 1 px/thread ----
    int r = t >> 5;          // 0..7
    int c = t & 31;          // 0..31
    int h = h0 + r;
    int w = w0 + c;

    uint32_t nb[3][3];
#pragma unroll
    for (int dr = 0; dr < 3; ++dr) {
        const uint32_t* rp = &sbits[(r + dr) * HALO_W + c];
        nb[dr][0] = rp[0]; nb[dr][1] = rp[1]; nb[dr][2] = rp[2];
    }

    const float* xp = xn + h * W + w;
    float y[32];
    uint32_t yb = 0;
#pragma unroll
    for (int oc = 0; oc < 32; ++oc) {
        int s = 0;
#pragma unroll
        for (int dr = 0; dr < 3; ++dr)
#pragma unroll
            for (int dc = 0; dc < 3; ++dc)
                s += __popc(nb[dr][dc] ^ wsu[oc * 9 + dr * 3 + dc]);  // wsu: s_load
        y[oc] = fmaf((float)(288 - 2 * s), wf[320 + oc], wf[352 + oc]) + xp[oc * HW];
        yb |= (y[oc] < 0.0f) ? (1u << oc) : 0u;
    }

    float* op = out + n * CHW + h * W + w;
#pragma unroll
    for (int oc = 0; oc < 32; ++oc) {
        int cc = 32 - 2 * __popc(yb ^ wsu[288 + oc]);
        op[oc * HW] = fmaf((float)cc, wf[384 + oc], wf[416 + oc]) + y[oc];
    }
}

// Recompute border pixels exactly (true zero padding), bits taken straight
// from x (L2/L3-hot). 636 border px per image * 32 images = 20352 threads.
__global__ __launch_bounds__(256) void border_fix(const float* __restrict__ x,
                                                  const uint32_t* __restrict__ wsu,
                                                  float* __restrict__ out) {
    const float* wf = (const float*)wsu;
    int t = blockIdx.x * blockDim.x + threadIdx.x;
    if (t >= NB * 636) return;
    int n = t / 636, idx = t % 636;
    int h, w;
    if (idx < 160)      { h = 0;         w = idx; }
    else if (idx < 320) { h = H - 1;     w = idx - 160; }
    else if (idx < 478) { h = idx - 319; w = 0; }       // h = 1..158
    else                { h = idx - 477; w = W - 1; }   // h = 1..158

    const float* xn = x + n * CHW;
    uint32_t nb[3][3];
    int m[3][3];
#pragma unroll
    for (int r = 0; r < 3; ++r) {
        int hh = h + r - 1;
        bool rok = (hh >= 0) && (hh < H);
#pragma unroll
        for (int c = 0; c < 3; ++c) {
            int ww = w + c - 1;
            bool ok = rok && (ww >= 0) && (ww < W);
            m[r][c] = ok ? -1 : 0;
            uint32_t bits = 0;
            if (ok) {
                const float* xp = xn + hh * W + ww;
#pragma unroll
                for (int ch = 0; ch < 32; ++ch)
                    bits |= (xp[ch * HW] < 0.0f) ? (1u << ch) : 0u;
            }
            nb[r][c] = bits;
        }
    }

    const float* xp = xn + h * W + w;
    float y[32];
    uint32_t yb = 0;
#pragma unroll
    for (int oc = 0; oc < 32; ++oc) {
        int s = 0;
#pragma unroll
        for (int r = 0; r < 3; ++r) {
#pragma unroll
            for (int c = 0; c < 3; ++c) {
                uint32_t wv = wsu[oc * 9 + r * 3 + c];
                s += (32 - 2 * __popc(nb[r][c] ^ wv)) & m[r][c];
            }
        }
        float sc = wf[320 + oc], sh = wf[352 + oc];
        y[oc] = fmaf((float)s, sc, sh) + xp[oc * HW];
        yb |= (y[oc] < 0.0f) ? (1u << oc) : 0u;
    }
    float* op = out + n * CHW + h * W + w;
#pragma unroll
    for (int oc = 0; oc < 32; ++oc) {
        float sc = wf[384 + oc], sh = wf[416 + oc];
        int cc = 32 - 2 * __popc(yb ^ wsu[288 + oc]);
        op[oc * HW] = fmaf((float)cc, sc, sh) + y[oc];
    }
}

extern "C" void kernel_launch(void* const* d_in, const int* in_sizes, int n_in,
                              void* d_out, int out_size, void* d_ws, size_t ws_size,
                              hipStream_t stream) {
    const float* x  = (const float*)d_in[0];
    const float* w3 = (const float*)d_in[1];
    const float* g3 = (const float*)d_in[2];
    const float* b3 = (const float*)d_in[3];
    const float* m3 = (const float*)d_in[4];
    const float* v3 = (const float*)d_in[5];
    const float* w1 = (const float*)d_in[6];
    const float* g1 = (const float*)d_in[7];
    const float* b1 = (const float*)d_in[8];
    const float* m1 = (const float*)d_in[9];
    const float* v1 = (const float*)d_in[10];
    float* out = (float*)d_out;
    uint32_t* wsu = (uint32_t*)d_ws;

    pack_params<<<1, 320, 0, stream>>>(w3, g3, b3, m3, v3, w1, g1, b1, m1, v1, wsu);
    fused_tile<<<NB * TILES_PER_IMG, 256, 0, stream>>>(x, wsu, out);
    border_fix<<<(NB * 636 + 255) / 256, 256, 0, stream>>>(x, wsu, out);
}

// Round 8
// 93.741 us; speedup vs baseline: 1.9751x; 1.9751x over previous
//
#include <hip/hip_runtime.h>
#include <stdint.h>

#define C   32
#define H   160
#define W   160
#define NB  32
#define HW  (H * W)          // 25600
#define CHW (C * HW)         // 819200
#define NPIX (NB * HW)       // 819200
#define XBOFF 448            // xbits offset in d_ws (u32 units)

typedef float f32x2 __attribute__((ext_vector_type(2)));

// d_ws layout (uint32 units):
// [0,288)    w3bits  [oc*9 + kh*3 + kw], bit ic = (w3<0)
// [288,320)  w1bits  [oc], bit ic = (w1<0)
// [320,352)  scale3 (f32)   [352,384) shift3
// [384,416)  scale1 (f32)   [416,448) shift1
// [448,448+NPIX) xbits [n*HW + h*W + w], bit c = (x<0)

__global__ void pack_params(const float* __restrict__ w3,
                            const float* __restrict__ g3, const float* __restrict__ b3,
                            const float* __restrict__ m3, const float* __restrict__ v3,
                            const float* __restrict__ w1,
                            const float* __restrict__ g1, const float* __restrict__ b1,
                            const float* __restrict__ m1, const float* __restrict__ v1,
                            uint32_t* __restrict__ wsu) {
    int t = threadIdx.x;
    if (t < 288) {
        int oc = t / 9, tap = t % 9;
        uint32_t bits = 0;
#pragma unroll
        for (int ic = 0; ic < 32; ++ic)
            bits |= (w3[oc * 288 + ic * 9 + tap] < 0.0f) ? (1u << ic) : 0u;
        wsu[t] = bits;
    } else if (t < 320) {
        int oc = t - 288;
        uint32_t bits = 0;
#pragma unroll
        for (int ic = 0; ic < 32; ++ic)
            bits |= (w1[oc * 32 + ic] < 0.0f) ? (1u << ic) : 0u;
        wsu[288 + oc] = bits;
        float* f = (float*)wsu;
        float inv3 = g3[oc] * rsqrtf(v3[oc] + 1e-5f);
        f[320 + oc] = inv3;
        f[352 + oc] = b3[oc] - m3[oc] * inv3;
        float inv1 = g1[oc] * rsqrtf(v1[oc] + 1e-5f);
        f[384 + oc] = inv1;
        f[416 + oc] = b1[oc] - m1[oc] * inv1;
    }
}

__global__ __launch_bounds__(256) void pack_x(const float* __restrict__ x,
                                              uint32_t* __restrict__ xbits) {
    int i = blockIdx.x * blockDim.x + threadIdx.x;   // quad index
    if (i >= NPIX / 4) return;
    int p = i * 4;
    int n = p / HW;
    int r = p % HW;
    const float* xp = x + n * CHW + r;
    uint32_t b0 = 0, b1 = 0, b2 = 0, b3 = 0;
#pragma unroll
    for (int c = 0; c < 32; ++c) {
        float4 v = *reinterpret_cast<const float4*>(xp + c * HW);
        b0 |= (v.x < 0.0f) ? (1u << c) : 0u;
        b1 |= (v.y < 0.0f) ? (1u << c) : 0u;
        b2 |= (v.z < 0.0f) ? (1u << c) : 0u;
        b3 |= (v.w < 0.0f) ? (1u << c) : 0u;
    }
    *reinterpret_cast<uint4*>(xbits + p) = make_uint4(b0, b1, b2, b3);
}

// 2 px/thread (R2-proven body). Branch-free interior formula for all pixels;
// image-border pixels come out wrong (clamped neighborhood) and are
// overwritten by border_fix afterwards (stream-ordered).
// Output stores are NON-TEMPORAL: out is write-only, keep L2/L3 for x+bits.
__global__ __launch_bounds__(256) void fused_main(const float* __restrict__ x,
                                                  const uint32_t* __restrict__ wsu,
                                                  float* __restrict__ out) {
    const float* wf = (const float*)wsu;
    int pi = blockIdx.x * blockDim.x + threadIdx.x;  // pixel-pair index, exact grid
    int p0  = pi * 2;
    int n   = p0 / HW;
    int rem = p0 % HW;
    int h   = rem / W;
    int w   = rem % W;          // even; pair covers columns w, w+1

    const uint32_t* xbn = wsu + XBOFF + n * HW;

    int hm1 = (h > 0) ? h - 1 : 0;
    int hp1 = (h < H - 1) ? h + 1 : H - 1;
    int wm1 = (w > 0) ? w - 1 : 0;
    int wp2 = (w < W - 2) ? w + 2 : W - 1;

    uint32_t nb[3][4];
    {
        const uint32_t* r0 = xbn + hm1 * W;
        const uint32_t* r1 = xbn + h   * W;
        const uint32_t* r2 = xbn + hp1 * W;
        nb[0][0] = r0[wm1]; nb[0][1] = r0[w]; nb[0][2] = r0[w + 1]; nb[0][3] = r0[wp2];
        nb[1][0] = r1[wm1]; nb[1][1] = r1[w]; nb[1][2] = r1[w + 1]; nb[1][3] = r1[wp2];
        nb[2][0] = r2[wm1]; nb[2][1] = r2[w]; nb[2][2] = r2[w + 1]; nb[2][3] = r2[wp2];
    }

    const float* xrow = x + n * CHW + h * W + w;
    float y0[32], y1[32];

#pragma unroll
    for (int oc = 0; oc < 32; ++oc) {
        int s0 = 0, s1 = 0;
#pragma unroll
        for (int r = 0; r < 3; ++r) {
#pragma unroll
            for (int c = 0; c < 3; ++c) {
                uint32_t wv = wsu[oc * 9 + r * 3 + c];   // uniform -> s_load
                s0 += __popc(nb[r][c] ^ wv);
                s1 += __popc(nb[r][c + 1] ^ wv);
            }
        }
        float sc = wf[320 + oc], sh = wf[352 + oc];      // uniform -> s_load
        float2 xv = *reinterpret_cast<const float2*>(xrow + oc * HW);
        y0[oc] = fmaf((float)(288 - 2 * s0), sc, sh) + xv.x;
        y1[oc] = fmaf((float)(288 - 2 * s1), sc, sh) + xv.y;
    }

    uint32_t yb0 = 0, yb1 = 0;
#pragma unroll
    for (int oc = 0; oc < 32; ++oc) {
        yb0 |= (y0[oc] < 0.0f) ? (1u << oc) : 0u;
        yb1 |= (y1[oc] < 0.0f) ? (1u << oc) : 0u;
    }
    float* orow = out + n * CHW + h * W + w;
#pragma unroll
    for (int oc = 0; oc < 32; ++oc) {
        float sc = wf[384 + oc], sh = wf[416 + oc];
        int c0 = 32 - 2 * __popc(yb0 ^ wsu[288 + oc]);
        int c1 = 32 - 2 * __popc(yb1 ^ wsu[288 + oc]);
        f32x2 zv;
        zv.x = fmaf((float)c0, sc, sh) + y0[oc];
        zv.y = fmaf((float)c1, sc, sh) + y1[oc];
        __builtin_nontemporal_store(zv, (f32x2*)(orow + oc * HW));
    }
}

// Recompute border pixels exactly (true zero-padding masks) from packed bits.
// 636 border pixels per image * 32 images = 20352 threads.
__global__ __launch_bounds__(256) void border_fix(const float* __restrict__ x,
                                                  const uint32_t* __restrict__ wsu,
                                                  float* __restrict__ out) {
    const float* wf = (const float*)wsu;
    int t = blockIdx.x * blockDim.x + threadIdx.x;
    if (t >= NB * 636) return;
    int n = t / 636, idx = t % 636;
    int h, w;
    if (idx < 160)      { h = 0;         w = idx; }
    else if (idx < 320) { h = H - 1;     w = idx - 160; }
    else if (idx < 478) { h = idx - 319; w = 0; }       // h = 1..158
    else                { h = idx - 477; w = W - 1; }   // h = 1..158

    const uint32_t* xbn = wsu + XBOFF + n * HW;
    uint32_t nb[3][3];
    int m[3][3];
#pragma unroll
    for (int r = 0; r < 3; ++r) {
        int hh = h + r - 1;
        bool rok = (hh >= 0) && (hh < H);
#pragma unroll
        for (int c = 0; c < 3; ++c) {
            int ww = w + c - 1;
            bool ok = rok && (ww >= 0) && (ww < W);
            m[r][c]  = ok ? -1 : 0;
            nb[r][c] = ok ? xbn[hh * W + ww] : 0u;
        }
    }

    const float* xp = x + n * CHW + h * W + w;
    float y[32];
    uint32_t yb = 0;
#pragma unroll
    for (int oc = 0; oc < 32; ++oc) {
        int s = 0;
#pragma unroll
        for (int r = 0; r < 3; ++r) {
#pragma unroll
            for (int c = 0; c < 3; ++c) {
                uint32_t wv = wsu[oc * 9 + r * 3 + c];
                s += (32 - 2 * __popc(nb[r][c] ^ wv)) & m[r][c];
            }
        }
        float sc = wf[320 + oc], sh = wf[352 + oc];
        y[oc] = fmaf((float)s, sc, sh) + xp[oc * HW];
        yb |= (y[oc] < 0.0f) ? (1u << oc) : 0u;
    }
    float* op = out + n * CHW + h * W + w;
#pragma unroll
    for (int oc = 0; oc < 32; ++oc) {
        float sc = wf[384 + oc], sh = wf[416 + oc];
        int cc = 32 - 2 * __popc(yb ^ wsu[288 + oc]);
        op[oc * HW] = fmaf((float)cc, sc, sh) + y[oc];
    }
}

extern "C" void kernel_launch(void* const* d_in, const int* in_sizes, int n_in,
                              void* d_out, int out_size, void* d_ws, size_t ws_size,
                              hipStream_t stream) {
    const float* x  = (const float*)d_in[0];
    const float* w3 = (const float*)d_in[1];
    const float* g3 = (const float*)d_in[2];
    const float* b3 = (const float*)d_in[3];
    const float* m3 = (const float*)d_in[4];
    const float* v3 = (const float*)d_in[5];
    const float* w1 = (const float*)d_in[6];
    const float* g1 = (const float*)d_in[7];
    const float* b1 = (const float*)d_in[8];
    const float* m1 = (const float*)d_in[9];
    const float* v1 = (const float*)d_in[10];
    float* out = (float*)d_out;
    uint32_t* wsu = (uint32_t*)d_ws;

    pack_params<<<1, 320, 0, stream>>>(w3, g3, b3, m3, v3, w1, g1, b1, m1, v1, wsu);
    pack_x<<<NPIX / 4 / 256, 256, 0, stream>>>(x, wsu + XBOFF);
    fused_main<<<NPIX / 2 / 256, 256, 0, stream>>>(x, wsu, out);
    border_fix<<<(NB * 636 + 255) / 256, 256, 0, stream>>>(x, wsu, out);
}

// Round 10
// 85.500 us; speedup vs baseline: 2.1654x; 1.0964x over previous
//
#include <hip/hip_runtime.h>
#include <stdint.h>

#define C   32
#define H   160
#define W   160
#define NB  32
#define HW  (H * W)          // 25600
#define CHW (C * HW)         // 819200
#define NPIX (NB * HW)       // 819200
#define XBOFF 448            // xbits offset in d_ws (u32 units)

// d_ws layout (uint32 units):
// [0,288)    w3bits [oc*9 + kh*3 + kw], bit ic = (w3<0)
// [288,320)  w1bits [oc], bit ic = (w1<0)
// f[320,352) inv3   f[352,384) sh3 = b3 - m3*inv3
// f[384,416) inv1   f[416,448) sh1 = b1 - m1*inv1
// [448,448+NPIX) xbits [n*HW + h*W + w], bit c = (x<0)

__global__ void pack_params(const float* __restrict__ w3,
                            const float* __restrict__ g3, const float* __restrict__ b3,
                            const float* __restrict__ m3, const float* __restrict__ v3,
                            const float* __restrict__ w1,
                            const float* __restrict__ g1, const float* __restrict__ b1,
                            const float* __restrict__ m1, const float* __restrict__ v1,
                            uint32_t* __restrict__ wsu) {
    int t = threadIdx.x;
    if (t < 288) {
        int oc = t / 9, tap = t % 9;
        uint32_t bits = 0;
#pragma unroll
        for (int ic = 0; ic < 32; ++ic)
            bits |= (w3[oc * 288 + ic * 9 + tap] < 0.0f) ? (1u << ic) : 0u;
        wsu[t] = bits;
    } else if (t < 320) {
        int oc = t - 288;
        uint32_t bits = 0;
#pragma unroll
        for (int ic = 0; ic < 32; ++ic)
            bits |= (w1[oc * 32 + ic] < 0.0f) ? (1u << ic) : 0u;
        wsu[288 + oc] = bits;
        float* f = (float*)wsu;
        float inv3 = g3[oc] * rsqrtf(v3[oc] + 1e-5f);
        f[320 + oc] = inv3;
        f[352 + oc] = b3[oc] - m3[oc] * inv3;
        float inv1 = g1[oc] * rsqrtf(v1[oc] + 1e-5f);
        f[384 + oc] = inv1;
        f[416 + oc] = b1[oc] - m1[oc] * inv1;
    }
}

__global__ __launch_bounds__(256) void pack_x(const float* __restrict__ x,
                                              uint32_t* __restrict__ xbits) {
    int i = blockIdx.x * blockDim.x + threadIdx.x;   // quad index
    if (i >= NPIX / 4) return;
    int p = i * 4;
    int n = p / HW;
    int r = p % HW;
    const float* xp = x + n * CHW + r;
    uint32_t b0 = 0, b1 = 0, b2 = 0, b3 = 0;
#pragma unroll
    for (int c = 0; c < 32; ++c) {
        float4 v = *reinterpret_cast<const float4*>(xp + c * HW);
        b0 |= (v.x < 0.0f) ? (1u << c) : 0u;
        b1 |= (v.y < 0.0f) ? (1u << c) : 0u;
        b2 |= (v.z < 0.0f) ? (1u << c) : 0u;
        b3 |= (v.w < 0.0f) ? (1u << c) : 0u;
    }
    *reinterpret_cast<uint4*>(xbits + p) = make_uint4(b0, b1, b2, b3);
}

// 2 px/thread, R2-proven arithmetic (y = fma(288-2s, inv3, sh3) + x), oc-loop
// chunked 4x8 with all 8 float2 x-loads issued before their consumers
// (MLP ~8 outstanding loads/wave). Branch-free interior formula for all
// pixels; image-border pixels are wrong here and overwritten by border_fix.
__global__ __launch_bounds__(256) void fused_main(const float* __restrict__ x,
                                                  const uint32_t* __restrict__ wsu,
                                                  float* __restrict__ out) {
    const float* wf = (const float*)wsu;
    int pi = blockIdx.x * blockDim.x + threadIdx.x;  // pixel-pair index, exact grid
    int p0  = pi * 2;
    int n   = p0 / HW;
    int rem = p0 % HW;
    int h   = rem / W;
    int w   = rem % W;          // even; pair covers columns w, w+1

    const uint32_t* xbn = wsu + XBOFF + n * HW;

    int hm1 = (h > 0) ? h - 1 : 0;
    int hp1 = (h < H - 1) ? h + 1 : H - 1;
    int wm1 = (w > 0) ? w - 1 : 0;
    int wp2 = (w < W - 2) ? w + 2 : W - 1;

    uint32_t nb[3][4];
    {
        const uint32_t* r0 = xbn + hm1 * W;
        const uint32_t* r1 = xbn + h   * W;
        const uint32_t* r2 = xbn + hp1 * W;
        nb[0][0] = r0[wm1]; nb[0][1] = r0[w]; nb[0][2] = r0[w + 1]; nb[0][3] = r0[wp2];
        nb[1][0] = r1[wm1]; nb[1][1] = r1[w]; nb[1][2] = r1[w + 1]; nb[1][3] = r1[wp2];
        nb[2][0] = r2[wm1]; nb[2][1] = r2[w]; nb[2][2] = r2[w + 1]; nb[2][3] = r2[wp2];
    }

    const float* xrow = x + n * CHW + h * W + w;
    float y0[32], y1[32];
    uint32_t yb0 = 0, yb1 = 0;

#pragma unroll
    for (int ck = 0; ck < 4; ++ck) {
        float2 xv[8];
#pragma unroll
        for (int j = 0; j < 8; ++j)
            xv[j] = *reinterpret_cast<const float2*>(xrow + (ck * 8 + j) * HW);
#pragma unroll
        for (int j = 0; j < 8; ++j) {
            int oc = ck * 8 + j;
            int s0 = 0, s1 = 0;
#pragma unroll
            for (int r = 0; r < 3; ++r) {
#pragma unroll
                for (int c = 0; c < 3; ++c) {
                    uint32_t wv = wsu[oc * 9 + r * 3 + c];   // uniform -> s_load
                    s0 += __popc(nb[r][c] ^ wv);
                    s1 += __popc(nb[r][c + 1] ^ wv);
                }
            }
            float sc = wf[320 + oc], sh = wf[352 + oc];      // uniform -> s_load
            y0[oc] = fmaf((float)(288 - 2 * s0), sc, sh) + xv[j].x;
            y1[oc] = fmaf((float)(288 - 2 * s1), sc, sh) + xv[j].y;
            yb0 |= (y0[oc] < 0.0f) ? (1u << oc) : 0u;
            yb1 |= (y1[oc] < 0.0f) ? (1u << oc) : 0u;
        }
    }

    float* orow = out + n * CHW + h * W + w;
#pragma unroll
    for (int oc = 0; oc < 32; ++oc) {
        float sc = wf[384 + oc], sh = wf[416 + oc];
        uint32_t wb = wsu[288 + oc];
        int c0 = 32 - 2 * __popc(yb0 ^ wb);
        int c1 = 32 - 2 * __popc(yb1 ^ wb);
        float2 zv;
        zv.x = fmaf((float)c0, sc, sh) + y0[oc];
        zv.y = fmaf((float)c1, sc, sh) + y1[oc];
        *reinterpret_cast<float2*>(orow + oc * HW) = zv;
    }
}

// Recompute border pixels exactly (true zero-padding masks) from packed bits.
// 636 border pixels per image * 32 images = 20352 threads.
__global__ __launch_bounds__(256) void border_fix(const float* __restrict__ x,
                                                  const uint32_t* __restrict__ wsu,
                                                  float* __restrict__ out) {
    const float* wf = (const float*)wsu;
    int t = blockIdx.x * blockDim.x + threadIdx.x;
    if (t >= NB * 636) return;
    int n = t / 636, idx = t % 636;
    int h, w;
    if (idx < 160)      { h = 0;         w = idx; }
    else if (idx < 320) { h = H - 1;     w = idx - 160; }
    else if (idx < 478) { h = idx - 319; w = 0; }       // h = 1..158
    else                { h = idx - 477; w = W - 1; }   // h = 1..158

    const uint32_t* xbn = wsu + XBOFF + n * HW;
    uint32_t nb[3][3];
    int m[3][3];
#pragma unroll
    for (int r = 0; r < 3; ++r) {
        int hh = h + r - 1;
        bool rok = (hh >= 0) && (hh < H);
#pragma unroll
        for (int c = 0; c < 3; ++c) {
            int ww = w + c - 1;
            bool ok = rok && (ww >= 0) && (ww < W);
            m[r][c]  = ok ? -1 : 0;
            nb[r][c] = ok ? xbn[hh * W + ww] : 0u;
        }
    }

    const float* xp = x + n * CHW + h * W + w;
    float y[32];
    uint32_t yb = 0;
#pragma unroll
    for (int oc = 0; oc < 32; ++oc) {
        int s = 0;   // true conv value (masked taps contribute 0)
#pragma unroll
        for (int r = 0; r < 3; ++r) {
#pragma unroll
            for (int c = 0; c < 3; ++c) {
                uint32_t wv = wsu[oc * 9 + r * 3 + c];
                s += (32 - 2 * __popc(nb[r][c] ^ wv)) & m[r][c];
            }
        }
        float sc = wf[320 + oc], sh = wf[352 + oc];
        y[oc] = fmaf((float)s, sc, sh) + xp[oc * HW];
        yb |= (y[oc] < 0.0f) ? (1u << oc) : 0u;
    }
    float* op = out + n * CHW + h * W + w;
#pragma unroll
    for (int oc = 0; oc < 32; ++oc) {
        float sc = wf[384 + oc], sh = wf[416 + oc];
        int cc = 32 - 2 * __popc(yb ^ wsu[288 + oc]);
        op[oc * HW] = fmaf((float)cc, sc, sh) + y[oc];
    }
}

extern "C" void kernel_launch(void* const* d_in, const int* in_sizes, int n_in,
                              void* d_out, int out_size, void* d_ws, size_t ws_size,
                              hipStream_t stream) {
    const float* x  = (const float*)d_in[0];
    const float* w3 = (const float*)d_in[1];
    const float* g3 = (const float*)d_in[2];
    const float* b3 = (const float*)d_in[3];
    const float* m3 = (const float*)d_in[4];
    const float* v3 = (const float*)d_in[5];
    const float* w1 = (const float*)d_in[6];
    const float* g1 = (const float*)d_in[7];
    const float* b1 = (const float*)d_in[8];
    const float* m1 = (const float*)d_in[9];
    const float* v1 = (const float*)d_in[10];
    float* out = (float*)d_out;
    uint32_t* wsu = (uint32_t*)d_ws;

    pack_params<<<1, 320, 0, stream>>>(w3, g3, b3, m3, v3, w1, g1, b1, m1, v1, wsu);
    pack_x<<<NPIX / 4 / 256, 256, 0, stream>>>(x, wsu + XBOFF);
    fused_main<<<NPIX / 2 / 256, 256, 0, stream>>>(x, wsu, out);
    border_fix<<<(NB * 636 + 255) / 256, 256, 0, stream>>>(x, wsu, out);
}

// Round 11
// 83.526 us; speedup vs baseline: 2.2166x; 1.0236x over previous
//
#include <hip/hip_runtime.h>
#include <stdint.h>

#define C   32
#define H   160
#define W   160
#define NB  32
#define HW  (H * W)          // 25600
#define CHW (C * HW)         // 819200
#define NPIX (NB * HW)       // 819200
#define XBOFF 448            // xbits offset in d_ws (u32 units)

// d_ws layout (uint32 units):
// [0,288)    w3bits [oc*9 + kh*3 + kw], bit ic = (w3<0)
// [288,320)  w1bits [oc], bit ic = (w1<0)
// f[320,352) inv3   f[352,384) sh3 = b3 - m3*inv3
// f[384,416) inv1   f[416,448) sh1 = b1 - m1*inv1
// [448,448+NPIX) xbits [n*HW + h*W + w], bit c = (x<0)

__global__ void pack_params(const float* __restrict__ w3,
                            const float* __restrict__ g3, const float* __restrict__ b3,
                            const float* __restrict__ m3, const float* __restrict__ v3,
                            const float* __restrict__ w1,
                            const float* __restrict__ g1, const float* __restrict__ b1,
                            const float* __restrict__ m1, const float* __restrict__ v1,
                            uint32_t* __restrict__ wsu) {
    int t = threadIdx.x;
    if (t < 288) {
        int oc = t / 9, tap = t % 9;
        uint32_t bits = 0;
#pragma unroll
        for (int ic = 0; ic < 32; ++ic)
            bits |= (w3[oc * 288 + ic * 9 + tap] < 0.0f) ? (1u << ic) : 0u;
        wsu[t] = bits;
    } else if (t < 320) {
        int oc = t - 288;
        uint32_t bits = 0;
#pragma unroll
        for (int ic = 0; ic < 32; ++ic)
            bits |= (w1[oc * 32 + ic] < 0.0f) ? (1u << ic) : 0u;
        wsu[288 + oc] = bits;
        float* f = (float*)wsu;
        float inv3 = g3[oc] * rsqrtf(v3[oc] + 1e-5f);
        f[320 + oc] = inv3;
        f[352 + oc] = b3[oc] - m3[oc] * inv3;
        float inv1 = g1[oc] * rsqrtf(v1[oc] + 1e-5f);
        f[384 + oc] = inv1;
        f[416 + oc] = b1[oc] - m1[oc] * inv1;
    }
}

__global__ __launch_bounds__(256) void pack_x(const float* __restrict__ x,
                                              uint32_t* __restrict__ xbits) {
    int i = blockIdx.x * blockDim.x + threadIdx.x;   // quad index
    if (i >= NPIX / 4) return;
    int p = i * 4;
    int n = p / HW;
    int r = p % HW;
    const float* xp = x + n * CHW + r;
    uint32_t b0 = 0, b1 = 0, b2 = 0, b3 = 0;
#pragma unroll
    for (int c = 0; c < 32; ++c) {
        float4 v = *reinterpret_cast<const float4*>(xp + c * HW);
        b0 |= (v.x < 0.0f) ? (1u << c) : 0u;
        b1 |= (v.y < 0.0f) ? (1u << c) : 0u;
        b2 |= (v.z < 0.0f) ? (1u << c) : 0u;
        b3 |= (v.w < 0.0f) ? (1u << c) : 0u;
    }
    *reinterpret_cast<uint4*>(xbits + p) = make_uint4(b0, b1, b2, b3);
}

// 1 px/thread (R4-proven body shape: VGPR ~32, high occupancy), linear pixel
// indexing so each wave covers 64 consecutive columns of one row: all x loads,
// bit loads, and out stores are 256 B/wave contiguous. Bits come from the
// precomputed global xbits (3.3 MB, L2-resident) -- no halo re-pack, no LDS.
// Branch-free interior formula for all pixels; image-border pixels are wrong
// (clamped neighborhood) and are overwritten by border_fix afterwards.
__global__ __launch_bounds__(256) void fused_main(const float* __restrict__ x,
                                                  const uint32_t* __restrict__ wsu,
                                                  float* __restrict__ out) {
    const float* wf = (const float*)wsu;
    int p   = blockIdx.x * blockDim.x + threadIdx.x;  // pixel index, exact grid
    int n   = p / HW;
    int rem = p % HW;
    int h   = rem / W;
    int w   = rem % W;

    const uint32_t* xbn = wsu + XBOFF + n * HW;

    int hm1 = (h > 0) ? h - 1 : 0;
    int hp1 = (h < H - 1) ? h + 1 : H - 1;
    int wm1 = (w > 0) ? w - 1 : 0;
    int wp1 = (w < W - 1) ? w + 1 : W - 1;

    uint32_t nb[3][3];
    {
        const uint32_t* r0 = xbn + hm1 * W;
        const uint32_t* r1 = xbn + h   * W;
        const uint32_t* r2 = xbn + hp1 * W;
        nb[0][0] = r0[wm1]; nb[0][1] = r0[w]; nb[0][2] = r0[wp1];
        nb[1][0] = r1[wm1]; nb[1][1] = r1[w]; nb[1][2] = r1[wp1];
        nb[2][0] = r2[wm1]; nb[2][1] = r2[w]; nb[2][2] = r2[wp1];
    }

    const float* xp = x + n * CHW + h * W + w;
    float y[32];
    uint32_t yb = 0;
#pragma unroll
    for (int oc = 0; oc < 32; ++oc) {
        int s = 0;
#pragma unroll
        for (int r = 0; r < 3; ++r)
#pragma unroll
            for (int c = 0; c < 3; ++c)
                s += __popc(nb[r][c] ^ wsu[oc * 9 + r * 3 + c]);  // uniform -> s_load
        float sc = wf[320 + oc], sh = wf[352 + oc];               // uniform -> s_load
        y[oc] = fmaf((float)(288 - 2 * s), sc, sh) + xp[oc * HW];
        yb |= (y[oc] < 0.0f) ? (1u << oc) : 0u;
    }

    float* op = out + n * CHW + h * W + w;
#pragma unroll
    for (int oc = 0; oc < 32; ++oc) {
        float sc = wf[384 + oc], sh = wf[416 + oc];
        int cc = 32 - 2 * __popc(yb ^ wsu[288 + oc]);
        op[oc * HW] = fmaf((float)cc, sc, sh) + y[oc];
    }
}

// Recompute border pixels exactly (true zero-padding masks) from packed bits.
// 636 border pixels per image * 32 images = 20352 threads.
__global__ __launch_bounds__(256) void border_fix(const float* __restrict__ x,
                                                  const uint32_t* __restrict__ wsu,
                                                  float* __restrict__ out) {
    const float* wf = (const float*)wsu;
    int t = blockIdx.x * blockDim.x + threadIdx.x;
    if (t >= NB * 636) return;
    int n = t / 636, idx = t % 636;
    int h, w;
    if (idx < 160)      { h = 0;         w = idx; }
    else if (idx < 320) { h = H - 1;     w = idx - 160; }
    else if (idx < 478) { h = idx - 319; w = 0; }       // h = 1..158
    else                { h = idx - 477; w = W - 1; }   // h = 1..158

    const uint32_t* xbn = wsu + XBOFF + n * HW;
    uint32_t nb[3][3];
    int m[3][3];
#pragma unroll
    for (int r = 0; r < 3; ++r) {
        int hh = h + r - 1;
        bool rok = (hh >= 0) && (hh < H);
#pragma unroll
        for (int c = 0; c < 3; ++c) {
            int ww = w + c - 1;
            bool ok = rok && (ww >= 0) && (ww < W);
            m[r][c]  = ok ? -1 : 0;
            nb[r][c] = ok ? xbn[hh * W + ww] : 0u;
        }
    }

    const float* xp = x + n * CHW + h * W + w;
    float y[32];
    uint32_t yb = 0;
#pragma unroll
    for (int oc = 0; oc < 32; ++oc) {
        int s = 0;   // true conv value (masked taps contribute 0)
#pragma unroll
        for (int r = 0; r < 3; ++r) {
#pragma unroll
            for (int c = 0; c < 3; ++c) {
                uint32_t wv = wsu[oc * 9 + r * 3 + c];
                s += (32 - 2 * __popc(nb[r][c] ^ wv)) & m[r][c];
            }
        }
        float sc = wf[320 + oc], sh = wf[352 + oc];
        y[oc] = fmaf((float)s, sc, sh) + xp[oc * HW];
        yb |= (y[oc] < 0.0f) ? (1u << oc) : 0u;
    }
    float* op = out + n * CHW + h * W + w;
#pragma unroll
    for (int oc = 0; oc < 32; ++oc) {
        float sc = wf[384 + oc], sh = wf[416 + oc];
        int cc = 32 - 2 * __popc(yb ^ wsu[288 + oc]);
        op[oc * HW] = fmaf((float)cc, sc, sh) + y[oc];
    }
}

extern "C" void kernel_launch(void* const* d_in, const int* in_sizes, int n_in,
                              void* d_out, int out_size, void* d_ws, size_t ws_size,
                              hipStream_t stream) {
    const float* x  = (const float*)d_in[0];
    const float* w3 = (const float*)d_in[1];
    const float* g3 = (const float*)d_in[2];
    const float* b3 = (const float*)d_in[3];
    const float* m3 = (const float*)d_in[4];
    const float* v3 = (const float*)d_in[5];
    const float* w1 = (const float*)d_in[6];
    const float* g1 = (const float*)d_in[7];
    const float* b1 = (const float*)d_in[8];
    const float* m1 = (const float*)d_in[9];
    const float* v1 = (const float*)d_in[10];
    float* out = (float*)d_out;
    uint32_t* wsu = (uint32_t*)d_ws;

    pack_params<<<1, 320, 0, stream>>>(w3, g3, b3, m3, v3, w1, g1, b1, m1, v1, wsu);
    pack_x<<<NPIX / 4 / 256, 256, 0, stream>>>(x, wsu + XBOFF);
    fused_main<<<NPIX / 256, 256, 0, stream>>>(x, wsu, out);
    border_fix<<<(NB * 636 + 255) / 256, 256, 0, stream>>>(x, wsu, out);
}